// Round 1
// baseline (986.991 us; speedup 1.0000x reference)
//
#include <hip/hip_runtime.h>

#define TDIM 32768
#define KDIM 2048
#define NDIM 768
#define EDIM 64
#define RDIM 16
#define SCALE 2.0f

#define BM 128
#define BN 128
#define BKE 64     // K-step for the bf16 main kernel (128B LDS rows)
#define PK 40      // fallback kernel: padded LDS row length
#define MAXMT 320  // worst-case sum of ceil(m_e/BM) = T/BM + E = 256 + 64

typedef __bf16 bf16;
typedef __attribute__((ext_vector_type(8))) __bf16 bf16x8;
typedef __attribute__((ext_vector_type(4))) __bf16 bf16x4;
typedef __attribute__((ext_vector_type(4))) float f32x4;

// async global->LDS, 16B per lane; LDS dest = wave-uniform base + lane*16
#define GLOAD16(gp, lp) \
    __builtin_amdgcn_global_load_lds((const __attribute__((address_space(1))) void*)(gp), \
                                     (__attribute__((address_space(3))) void*)(lp), 16, 0, 0)

// ============================================================================
// Pass 1a: x fp32 -> bf16 (elementwise)
// ============================================================================
__global__ __launch_bounds__(256)
void conv_x_k(const float* __restrict__ x, bf16* __restrict__ xb)
{
    size_t i = ((size_t)blockIdx.x * 256 + threadIdx.x) * 8;
    float4 f0 = *reinterpret_cast<const float4*>(x + i);
    float4 f1 = *reinterpret_cast<const float4*>(x + i + 4);
    bf16x8 v;
    v[0] = (bf16)f0.x; v[1] = (bf16)f0.y; v[2] = (bf16)f0.z; v[3] = (bf16)f0.w;
    v[4] = (bf16)f1.x; v[5] = (bf16)f1.y; v[6] = (bf16)f1.z; v[7] = (bf16)f1.w;
    *reinterpret_cast<bf16x8*>(xb + i) = v;
}

// ============================================================================
// Pass 1b: w_base [E][K][N] fp32 -> wT [E][N][K] bf16 (transpose + convert)
// tile: 64 k x 32 n per block
// ============================================================================
__global__ __launch_bounds__(256)
void conv_w_k(const float* __restrict__ w, bf16* __restrict__ wT)
{
    __shared__ bf16 t[32][65];
    const int e  = blockIdx.z;
    const int n0 = blockIdx.x * 32;
    const int k0 = blockIdx.y * 64;
    const float* src = w + (size_t)e * KDIM * NDIM;
    #pragma unroll
    for (int i = 0; i < 8; ++i) {
        int lin = threadIdx.x + i * 256;
        int k = lin >> 5;          // 0..63
        int c = lin & 31;          // n within tile
        t[c][k] = (bf16)src[(size_t)(k0 + k) * NDIM + n0 + c];
    }
    __syncthreads();
    bf16* dst = wT + ((size_t)e * NDIM + n0) * KDIM + k0;
    #pragma unroll
    for (int i = 0; i < 8; ++i) {
        int lin = threadIdx.x + i * 256;
        int n = lin >> 6;          // 0..31
        int k = lin & 63;
        dst[(size_t)n * KDIM + k] = t[n][k];
    }
}

// ============================================================================
// Pass 1c: w_a [E][K][R] -> waT [E][R][K] bf16, plus tile-info table
// blockIdx.x < 16 : transpose chunk (e=blockIdx.y, k-chunk of 128)
// blockIdx.x ==16, y==0 : build tinfo[tile] = {e, tstart, rows, 0}
// ============================================================================
__global__ __launch_bounds__(256)
void prep_small_k(const float* __restrict__ w_a, const int* __restrict__ m_sizes,
                  bf16* __restrict__ waT, int4* __restrict__ tinfo)
{
    if (blockIdx.x < 16) {
        __shared__ bf16 t[RDIM][132];
        const int e  = blockIdx.y;
        const int k0 = blockIdx.x * 128;
        const float* src = w_a + ((size_t)e * KDIM + k0) * RDIM;
        #pragma unroll
        for (int i = 0; i < 8; ++i) {
            int lin = threadIdx.x + i * 256;   // 0..2047 = 128k x 16r
            int k = lin >> 4, r = lin & 15;
            t[r][k] = (bf16)src[lin];
        }
        __syncthreads();
        bf16* dst = waT + (size_t)e * RDIM * KDIM + k0;
        #pragma unroll
        for (int i = 0; i < 8; ++i) {
            int lin = threadIdx.x + i * 256;
            int r = lin >> 7, k = lin & 127;
            dst[(size_t)r * KDIM + k] = t[r][k];
        }
    } else if (blockIdx.y == 0) {
        for (int i = threadIdx.x; i < MAXMT; i += 256)
            tinfo[i] = make_int4(0, 0, 0, 0);
        __syncthreads();
        if (threadIdx.x < 64) {
            const int lane = threadIdx.x;
            int m  = m_sizes[lane];
            int nt = (m + BM - 1) >> 7;
            int pm = m, pt = nt;
            #pragma unroll
            for (int d = 1; d < 64; d <<= 1) {
                int vm = __shfl_up(pm, d);
                int vt = __shfl_up(pt, d);
                if (lane >= d) { pm += vm; pt += vt; }
            }
            int row0 = pm - m, tb = pt - nt;
            for (int tI = 0; tI < nt; ++tI) {
                int rr = m - (tI << 7); if (rr > BM) rr = BM;
                tinfo[tb + tI] = make_int4(lane, row0 + (tI << 7), rr, 0);
            }
        }
    }
}

// ============================================================================
// Pass 2: fused ragged GEMM + LoRA, pure bf16, global_load_lds staging.
// LDS rows are 128B (BKE=64 bf16); XOR-granule swizzle:
//   LDS[row][16B-granule g] holds global[row][g ^ (row&7)]
// achieved by pre-swizzling the per-lane GLOBAL source address (linear LDS
// dest, rule #21) and XOR-ing the same pattern on every ds_read.
// ============================================================================
__global__ __launch_bounds__(256, 2)
void lora_moe_bf16(const bf16* __restrict__ xb,
                   const bf16* __restrict__ wT,
                   const bf16* __restrict__ waT,
                   const float* __restrict__ w_b,
                   const int4* __restrict__ tinfo,
                   float* __restrict__ out)
{
    __shared__ bf16 As[BM][BKE];       // x tile        [m][k]
    __shared__ bf16 Bs[BN][BKE];       // w_base^T tile [n][k]
    __shared__ bf16 WaS[RDIM][BKE];    // w_a^T tile    [r][k]

    const int tid  = threadIdx.x;
    const int lane = tid & 63;
    const int wave = tid >> 6;
    const int wm   = wave >> 1;
    const int wn   = wave & 1;
    const int quad = lane >> 4;
    const int lrow = lane & 15;

    const int4 ti = tinfo[blockIdx.y];
    const int rows = ti.z;
    if (rows == 0) return;
    const int e      = ti.x;
    const int tstart = ti.y;
    const int n0     = blockIdx.x * BN;

    const bf16* a_base  = xb  + (size_t)tstart * KDIM;
    const bf16* b_base  = wT  + ((size_t)e * NDIM + n0) * KDIM;
    const bf16* wa_base = waT + (size_t)e * RDIM * KDIM;
    const float* wbb_e  = w_b + (size_t)e * RDIM * NDIM;

    f32x4 acc[4][4];
    f32x4 accA[4];
    #pragma unroll
    for (int i = 0; i < 4; ++i) {
        accA[i] = (f32x4){0.f, 0.f, 0.f, 0.f};
        #pragma unroll
        for (int j = 0; j < 4; ++j) acc[i][j] = (f32x4){0.f, 0.f, 0.f, 0.f};
    }

    // staging: each wave stages 32 rows of A and 32 rows of B (4 instrs each,
    // 8 rows/instr), waves 0-1 stage 8 rows of WaS each (1 instr).
    const int lr8 = lane >> 3;   // sub-row within 8-row chunk
    const int lg  = lane & 7;    // 16B-granule index within 128B row

    const bf16* agp[4];
    const bf16* bgp[4];
    #pragma unroll
    for (int i = 0; i < 4; ++i) {
        int r  = wave * 32 + i * 8 + lr8;
        int gr = r < rows ? r : rows - 1;            // clamp ragged tail
        agp[i] = a_base + (size_t)gr * KDIM + ((lg ^ (r & 7)) << 3);
        bgp[i] = b_base + (size_t)r  * KDIM + ((lg ^ (r & 7)) << 3);
    }
    const bf16* wagp = wa_base + (size_t)(wave * 8 + lr8) * KDIM + ((lg ^ lr8) << 3);

    const int swzr = (lrow & 7) << 4;   // read-side XOR (row&7 == lrow&7 for all frag rows)

    for (int kk = 0; kk < KDIM; kk += BKE) {
        __syncthreads();
        #pragma unroll
        for (int i = 0; i < 4; ++i)
            GLOAD16(agp[i], &As[wave * 32 + i * 8][0]);
        #pragma unroll
        for (int i = 0; i < 4; ++i)
            GLOAD16(bgp[i], &Bs[wave * 32 + i * 8][0]);
        if (wave < 2)
            GLOAD16(wagp, &WaS[wave * 8][0]);
        #pragma unroll
        for (int i = 0; i < 4; ++i) { agp[i] += BKE; bgp[i] += BKE; }
        wagp += BKE;
        __syncthreads();

        #pragma unroll
        for (int kh = 0; kh < 2; ++kh) {
            const int cb = (kh * 64 + quad * 16) ^ swzr;
            bf16x8 af[4];
            #pragma unroll
            for (int i = 0; i < 4; ++i)
                af[i] = *reinterpret_cast<const bf16x8*>(
                            (const char*)&As[wm * 64 + i * 16 + lrow][0] + cb);
            bf16x8 wf = *reinterpret_cast<const bf16x8*>(
                            (const char*)&WaS[lrow][0] + cb);
            #pragma unroll
            for (int j = 0; j < 4; ++j) {
                bf16x8 bfr = *reinterpret_cast<const bf16x8*>(
                                 (const char*)&Bs[wn * 64 + j * 16 + lrow][0] + cb);
                #pragma unroll
                for (int i = 0; i < 4; ++i)
                    acc[i][j] = __builtin_amdgcn_mfma_f32_16x16x32_bf16(af[i], bfr, acc[i][j], 0, 0, 0);
            }
            #pragma unroll
            for (int i = 0; i < 4; ++i)
                accA[i] = __builtin_amdgcn_mfma_f32_16x16x32_bf16(af[i], wf, accA[i], 0, 0, 0);
        }
    }

    // ================= epilogue: acc += (a * SCALE) @ w_b =================
    __syncthreads();
    // a (C-layout: col=lane&15 is r, row=quad*4+reg) -> As[m][r], swizzled; pad r 16..31 with 0
    if (wn == 0) {
        #pragma unroll
        for (int i = 0; i < 4; ++i) {
            int mrow = wm * 64 + i * 16 + quad * 4;
            #pragma unroll
            for (int r = 0; r < 4; ++r) {
                int row = mrow + r;
                char* p = (char*)&As[row][0] + ((lrow * 2) ^ ((row & 7) << 4));
                *reinterpret_cast<bf16*>(p) = (bf16)(accA[i][r] * SCALE);
            }
        }
    } else {
        #pragma unroll
        for (int i = 0; i < 4; ++i) {
            int mrow = wm * 64 + i * 16 + quad * 4;
            #pragma unroll
            for (int r = 0; r < 4; ++r) {
                int row = mrow + r;
                char* p = (char*)&As[row][0] + ((32 + lrow * 2) ^ ((row & 7) << 4));
                *reinterpret_cast<bf16*>(p) = (bf16)0.f;
            }
        }
    }
    // stage w_b: [r][n] -> Bs[n][r], swizzled, zero-padded r=16..31
    {
        int n  = tid & 127;
        int r0 = (tid >> 7) * 8;
        const float* p = wbb_e + (size_t)r0 * NDIM + n0 + n;
        bf16x8 v;
        #pragma unroll
        for (int u = 0; u < 8; ++u) v[u] = (bf16)p[(size_t)u * NDIM];
        char* q = (char*)&Bs[n][0];
        *reinterpret_cast<bf16x8*>(q + ((r0 * 2) ^ ((n & 7) << 4))) = v;
        bf16x8 z = {};
        *reinterpret_cast<bf16x8*>(q + ((32 + r0 * 2) ^ ((n & 7) << 4))) = z;
    }
    __syncthreads();
    #pragma unroll
    for (int i = 0; i < 4; ++i) {
        const int cb2 = (quad * 16) ^ swzr;
        bf16x8 af2 = *reinterpret_cast<const bf16x8*>(
                         (const char*)&As[wm * 64 + i * 16 + lrow][0] + cb2);
        #pragma unroll
        for (int j = 0; j < 4; ++j) {
            bf16x8 bf2 = *reinterpret_cast<const bf16x8*>(
                             (const char*)&Bs[wn * 64 + j * 16 + lrow][0] + cb2);
            acc[i][j] = __builtin_amdgcn_mfma_f32_16x16x32_bf16(af2, bf2, acc[i][j], 0, 0, 0);
        }
    }

    // ---- store (mask rows beyond this expert's tile) ----
    #pragma unroll
    for (int i = 0; i < 4; ++i) {
        int mbase = wm * 64 + i * 16 + quad * 4;
        #pragma unroll
        for (int j = 0; j < 4; ++j) {
            int col = n0 + wn * 64 + j * 16 + lrow;
            #pragma unroll
            for (int r = 0; r < 4; ++r) {
                int mr = mbase + r;
                if (mr < rows)
                    out[(size_t)(tstart + mr) * NDIM + col] = acc[i][j][r];
            }
        }
    }
}

// ============================================================================
// Fallback (verified previous kernel) — used if workspace is too small.
// ============================================================================
__global__ __launch_bounds__(256, 2)
void lora_moe_kernel(const float* __restrict__ x,
                     const int* __restrict__ m_sizes,
                     const float* __restrict__ w_base,
                     const float* __restrict__ w_a,
                     const float* __restrict__ w_b,
                     float* __restrict__ out)
{
    __shared__ bf16 As[BM][PK];
    __shared__ bf16 Bs[BN][PK];
    __shared__ bf16 WaS[RDIM][PK];

    const int tid  = threadIdx.x;
    const int lane = tid & 63;
    const int wave = tid >> 6;
    const int wm   = wave >> 1;
    const int wn   = wave & 1;
    const int quad = lane >> 4;
    const int lrow = lane & 15;

    int tile = blockIdx.y;
    int e = -1, tstart = 0, rows = 0;
    {
        int row0 = 0, acc2 = 0;
        for (int i = 0; i < EDIM; ++i) {
            int m = m_sizes[i];
            int nt = (m + BM - 1) >> 7;
            if (tile < acc2 + nt) {
                e = i;
                int lt = tile - acc2;
                tstart = row0 + (lt << 7);
                rows = m - (lt << 7);
                if (rows > BM) rows = BM;
                break;
            }
            acc2 += nt;
            row0 += m;
        }
    }
    if (e < 0) return;

    const int n0 = blockIdx.x * BN;

    const float* wb_e  = w_base + (size_t)e * KDIM * NDIM;
    const float* wa_e  = w_a    + (size_t)e * KDIM * RDIM;
    const float* wbb_e = w_b    + (size_t)e * RDIM * NDIM;

    f32x4 acc[4][4];
    f32x4 accA[4];
    #pragma unroll
    for (int i = 0; i < 4; ++i) {
        accA[i] = (f32x4){0.f, 0.f, 0.f, 0.f};
        #pragma unroll
        for (int j = 0; j < 4; ++j) acc[i][j] = (f32x4){0.f, 0.f, 0.f, 0.f};
    }

    const int arow  = tid >> 1;
    const int akh   = (tid & 1) * 16;
    const int agrow = tstart + (arow < rows ? arow : rows - 1);
    const float* aptr = x + (size_t)agrow * KDIM + akh;

    const int bn  = tid & 127;
    const int bg0 = (tid >> 7) * 4;

    const int war = tid & 15;
    const int wag = tid >> 4;

    for (int kk = 0; kk < KDIM; kk += 32) {
        __syncthreads();
        {
            const float* p = aptr + kk;
            float4 f0 = *reinterpret_cast<const float4*>(p);
            float4 f1 = *reinterpret_cast<const float4*>(p + 4);
            float4 f2 = *reinterpret_cast<const float4*>(p + 8);
            float4 f3 = *reinterpret_cast<const float4*>(p + 12);
            bf16x8 v0, v1;
            v0[0]=(bf16)f0.x; v0[1]=(bf16)f0.y; v0[2]=(bf16)f0.z; v0[3]=(bf16)f0.w;
            v0[4]=(bf16)f1.x; v0[5]=(bf16)f1.y; v0[6]=(bf16)f1.z; v0[7]=(bf16)f1.w;
            v1[0]=(bf16)f2.x; v1[1]=(bf16)f2.y; v1[2]=(bf16)f2.z; v1[3]=(bf16)f2.w;
            v1[4]=(bf16)f3.x; v1[5]=(bf16)f3.y; v1[6]=(bf16)f3.z; v1[7]=(bf16)f3.w;
            *reinterpret_cast<bf16x8*>(&As[arow][akh])     = v0;
            *reinterpret_cast<bf16x8*>(&As[arow][akh + 8]) = v1;
        }
        {
            #pragma unroll
            for (int gi = 0; gi < 4; ++gi) {
                int k = (bg0 + gi) * 4;
                const float* p = wb_e + (size_t)(kk + k) * NDIM + n0 + bn;
                float a0 = p[0];
                float a1 = p[NDIM];
                float a2 = p[2 * NDIM];
                float a3 = p[3 * NDIM];
                bf16x4 v; v[0]=(bf16)a0; v[1]=(bf16)a1; v[2]=(bf16)a2; v[3]=(bf16)a3;
                *reinterpret_cast<bf16x4*>(&Bs[bn][k]) = v;
            }
        }
        if (wag < 8) {
            int k = wag * 4;
            const float* p = wa_e + (size_t)(kk + k) * RDIM + war;
            bf16x4 v;
            v[0]=(bf16)p[0]; v[1]=(bf16)p[RDIM]; v[2]=(bf16)p[2*RDIM]; v[3]=(bf16)p[3*RDIM];
            *reinterpret_cast<bf16x4*>(&WaS[war][k]) = v;
        }
        __syncthreads();
        bf16x8 af[4];
        #pragma unroll
        for (int i = 0; i < 4; ++i)
            af[i] = *reinterpret_cast<const bf16x8*>(&As[wm*64 + i*16 + lrow][quad*8]);
        bf16x8 wf = *reinterpret_cast<const bf16x8*>(&WaS[lrow][quad*8]);
        #pragma unroll
        for (int j = 0; j < 4; ++j) {
            bf16x8 bfr = *reinterpret_cast<const bf16x8*>(&Bs[wn*64 + j*16 + lrow][quad*8]);
            #pragma unroll
            for (int i = 0; i < 4; ++i)
                acc[i][j] = __builtin_amdgcn_mfma_f32_16x16x32_bf16(af[i], bfr, acc[i][j], 0, 0, 0);
        }
        #pragma unroll
        for (int i = 0; i < 4; ++i)
            accA[i] = __builtin_amdgcn_mfma_f32_16x16x32_bf16(af[i], wf, accA[i], 0, 0, 0);
    }

    __syncthreads();
    if (wn == 0) {
        #pragma unroll
        for (int i = 0; i < 4; ++i) {
            int mrow = wm*64 + i*16 + quad*4;
            #pragma unroll
            for (int r = 0; r < 4; ++r)
                As[mrow + r][lrow] = (bf16)(accA[i][r] * SCALE);
        }
    } else {
        #pragma unroll
        for (int i = 0; i < 4; ++i) {
            int mrow = wm*64 + i*16 + quad*4;
            #pragma unroll
            for (int r = 0; r < 4; ++r)
                As[mrow + r][16 + lrow] = (bf16)0.f;
        }
    }
    {
        int n  = tid & 127;
        int r0 = (tid >> 7) * 8;
        const float* p = wbb_e + (size_t)r0 * NDIM + n0 + n;
        bf16x8 v;
        #pragma unroll
        for (int u = 0; u < 8; ++u) v[u] = (bf16)p[(size_t)u * NDIM];
        *reinterpret_cast<bf16x8*>(&Bs[n][r0]) = v;
        bf16x8 z = {};
        *reinterpret_cast<bf16x8*>(&Bs[n][16 + r0]) = z;
    }
    __syncthreads();
    #pragma unroll
    for (int i = 0; i < 4; ++i) {
        bf16x8 af2 = *reinterpret_cast<const bf16x8*>(&As[wm*64 + i*16 + lrow][quad*8]);
        #pragma unroll
        for (int j = 0; j < 4; ++j) {
            bf16x8 bf2 = *reinterpret_cast<const bf16x8*>(&Bs[wn*64 + j*16 + lrow][quad*8]);
            acc[i][j] = __builtin_amdgcn_mfma_f32_16x16x32_bf16(af2, bf2, acc[i][j], 0, 0, 0);
        }
    }

    #pragma unroll
    for (int i = 0; i < 4; ++i) {
        int mbase = wm*64 + i*16 + quad*4;
        #pragma unroll
        for (int j = 0; j < 4; ++j) {
            int col = n0 + wn*64 + j*16 + lrow;
            #pragma unroll
            for (int r = 0; r < 4; ++r) {
                int mr = mbase + r;
                if (mr < rows)
                    out[(size_t)(tstart + mr) * NDIM + col] = acc[i][j][r];
            }
        }
    }
}

extern "C" void kernel_launch(void* const* d_in, const int* in_sizes, int n_in,
                              void* d_out, int out_size, void* d_ws, size_t ws_size,
                              hipStream_t stream) {
    const float* x       = (const float*)d_in[0];
    const int*   m_sizes = (const int*)  d_in[1];
    const float* w_base  = (const float*)d_in[2];
    const float* w_a     = (const float*)d_in[3];
    const float* w_b     = (const float*)d_in[4];
    float* out = (float*)d_out;

    const size_t off_xb  = 0;
    const size_t off_wT  = off_xb  + (size_t)TDIM * KDIM * sizeof(bf16);          // 128 MiB
    const size_t off_waT = off_wT  + (size_t)EDIM * NDIM * KDIM * sizeof(bf16);   // +192 MiB
    const size_t off_ti  = off_waT + (size_t)EDIM * RDIM * KDIM * sizeof(bf16);   // +4 MiB
    const size_t need    = off_ti  + (size_t)MAXMT * sizeof(int4);

    if (ws_size >= need) {
        bf16* xb   = (bf16*)((char*)d_ws + off_xb);
        bf16* wT   = (bf16*)((char*)d_ws + off_wT);
        bf16* waT  = (bf16*)((char*)d_ws + off_waT);
        int4* tinf = (int4*)((char*)d_ws + off_ti);

        conv_x_k<<<(TDIM * KDIM) / (256 * 8), 256, 0, stream>>>(x, xb);
        conv_w_k<<<dim3(NDIM / 32, KDIM / 64, EDIM), 256, 0, stream>>>(w_base, wT);
        prep_small_k<<<dim3(17, EDIM), 256, 0, stream>>>(w_a, m_sizes, waT, tinf);
        lora_moe_bf16<<<dim3(NDIM / BN, MAXMT), 256, 0, stream>>>(xb, wT, waT, w_b, tinf, out);
    } else {
        lora_moe_kernel<<<dim3(NDIM / BN, MAXMT), 256, 0, stream>>>(x, m_sizes, w_base, w_a, w_b, out);
    }
}

// Round 4
// 941.195 us; speedup vs baseline: 1.0487x; 1.0487x over previous
//
#include <hip/hip_runtime.h>

#define TDIM 32768
#define KDIM 2048
#define NDIM 768
#define EDIM 64
#define RDIM 16
#define SCALE 2.0f

#define BM 128
#define BN 128
#define BKE 64     // K-step for the bf16 main kernel (128B LDS rows)
#define PK 40      // fallback kernel: padded LDS row length
#define MAXMT 320  // worst-case sum of ceil(m_e/BM) = T/BM + E = 256 + 64
#define NTILES (NDIM / BN)        // 6
#define NWG (NTILES * MAXMT)      // 1920, divisible by 8

typedef __bf16 bf16;
typedef __attribute__((ext_vector_type(8))) __bf16 bf16x8;
typedef __attribute__((ext_vector_type(4))) __bf16 bf16x4;
typedef __attribute__((ext_vector_type(2))) __bf16 bf16x2;
typedef __attribute__((ext_vector_type(4))) float f32x4;

// async global->LDS, 16B per lane; LDS dest = wave-uniform base + lane*16
#define GLOAD16(gp, lp) \
    __builtin_amdgcn_global_load_lds((const __attribute__((address_space(1))) void*)(gp), \
                                     (__attribute__((address_space(3))) void*)(lp), 16, 0, 0)

// ============================================================================
// Pass 1a: x fp32 -> bf16 (elementwise)
// ============================================================================
__global__ __launch_bounds__(256)
void conv_x_k(const float* __restrict__ x, bf16* __restrict__ xb)
{
    size_t i = ((size_t)blockIdx.x * 256 + threadIdx.x) * 8;
    float4 f0 = *reinterpret_cast<const float4*>(x + i);
    float4 f1 = *reinterpret_cast<const float4*>(x + i + 4);
    bf16x8 v;
    v[0] = (bf16)f0.x; v[1] = (bf16)f0.y; v[2] = (bf16)f0.z; v[3] = (bf16)f0.w;
    v[4] = (bf16)f1.x; v[5] = (bf16)f1.y; v[6] = (bf16)f1.z; v[7] = (bf16)f1.w;
    *reinterpret_cast<bf16x8*>(xb + i) = v;
}

// ============================================================================
// Pass 1b: w_base [E][K][N] fp32 -> wT [E][N][K] bf16 (transpose + convert)
// 64k x 64n tile per block; float4 coalesced loads (256B/row), LDS-buffered
// transpose (pad 66 -> <=4-way), bf16x8 coalesced 16B stores (128B/n-row).
// ============================================================================
__global__ __launch_bounds__(256)
void conv_w_k(const float* __restrict__ w, bf16* __restrict__ wT)
{
    __shared__ bf16 t[64][66];
    const int e  = blockIdx.z;
    const int n0 = blockIdx.x * 64;
    const int k0 = blockIdx.y * 64;
    const float* src = w + (size_t)e * KDIM * NDIM + (size_t)k0 * NDIM + n0;
    #pragma unroll
    for (int i = 0; i < 4; ++i) {
        int lin = threadIdx.x + i * 256;   // float4 units, 0..1023
        int row = lin >> 4;                // k within tile
        int c4  = lin & 15;                // n/4 within tile
        float4 f = *reinterpret_cast<const float4*>(src + (size_t)row * NDIM + c4 * 4);
        bf16x2 v0, v1;
        v0[0] = (bf16)f.x; v0[1] = (bf16)f.y;
        v1[0] = (bf16)f.z; v1[1] = (bf16)f.w;
        *reinterpret_cast<bf16x2*>(&t[row][c4 * 4])     = v0;   // 4B aligned always
        *reinterpret_cast<bf16x2*>(&t[row][c4 * 4 + 2]) = v1;
    }
    __syncthreads();
    bf16* dst = wT + ((size_t)e * NDIM + n0) * KDIM + k0;
    #pragma unroll
    for (int i = 0; i < 2; ++i) {
        int lin = threadIdx.x + i * 256;   // 0..511
        int n  = lin >> 3;                 // n within tile
        int kc = lin & 7;                  // k-chunk of 8
        bf16x8 v;
        #pragma unroll
        for (int j = 0; j < 8; ++j) v[j] = t[kc * 8 + j][n];
        *reinterpret_cast<bf16x8*>(dst + (size_t)n * KDIM + kc * 8) = v;
    }
}

// ============================================================================
// Pass 1c: w_a [E][K][R] -> waT [E][R][K] bf16, plus tile-info table
// ============================================================================
__global__ __launch_bounds__(256)
void prep_small_k(const float* __restrict__ w_a, const int* __restrict__ m_sizes,
                  bf16* __restrict__ waT, int4* __restrict__ tinfo)
{
    if (blockIdx.x < 16) {
        __shared__ bf16 t[RDIM][132];
        const int e  = blockIdx.y;
        const int k0 = blockIdx.x * 128;
        const float* src = w_a + ((size_t)e * KDIM + k0) * RDIM;
        #pragma unroll
        for (int i = 0; i < 8; ++i) {
            int lin = threadIdx.x + i * 256;   // 0..2047 = 128k x 16r
            int k = lin >> 4, r = lin & 15;
            t[r][k] = (bf16)src[lin];
        }
        __syncthreads();
        bf16* dst = waT + (size_t)e * RDIM * KDIM + k0;
        #pragma unroll
        for (int i = 0; i < 8; ++i) {
            int lin = threadIdx.x + i * 256;
            int r = lin >> 7, k = lin & 127;
            dst[(size_t)r * KDIM + k] = t[r][k];
        }
    } else if (blockIdx.y == 0) {
        for (int i = threadIdx.x; i < MAXMT; i += 256)
            tinfo[i] = make_int4(0, 0, 0, 0);
        __syncthreads();
        if (threadIdx.x < 64) {
            const int lane = threadIdx.x;
            int m  = m_sizes[lane];
            int nt = (m + BM - 1) >> 7;
            int pm = m, pt = nt;
            #pragma unroll
            for (int d = 1; d < 64; d <<= 1) {
                int vm = __shfl_up(pm, d);
                int vt = __shfl_up(pt, d);
                if (lane >= d) { pm += vm; pt += vt; }
            }
            int row0 = pm - m, tb = pt - nt;
            for (int tI = 0; tI < nt; ++tI) {
                int rr = m - (tI << 7); if (rr > BM) rr = BM;
                tinfo[tb + tI] = make_int4(lane, row0 + (tI << 7), rr, 0);
            }
        }
    }
}

// ============================================================================
// Pass 2: fused ragged GEMM + LoRA, pure bf16, global_load_lds staging.
// 4 blocks/CU (LDS 34KB x 4 = 136KB); XCD-chunked bijective swizzle so each
// XCD processes ~40 consecutive m-tiles (n-tiles inner) -> B-panel L2 reuse.
// ============================================================================
__global__ __launch_bounds__(256, 4)
void lora_moe_bf16(const bf16* __restrict__ xb,
                   const bf16* __restrict__ wT,
                   const bf16* __restrict__ waT,
                   const float* __restrict__ w_b,
                   const int4* __restrict__ tinfo,
                   float* __restrict__ out)
{
    __shared__ bf16 As[BM][BKE];       // x tile        [m][k]
    __shared__ bf16 Bs[BN][BKE];       // w_base^T tile [n][k]
    __shared__ bf16 WaS[RDIM][BKE];    // w_a^T tile    [r][k]

    const int tid  = threadIdx.x;
    const int lane = tid & 63;
    const int wave = tid >> 6;
    const int wm   = wave >> 1;
    const int wn   = wave & 1;
    const int quad = lane >> 4;
    const int lrow = lane & 15;

    // XCD-chunked swizzle: lin -> (xcd = lin&7) gets contiguous chunk of work ids
    const int lin   = blockIdx.y * NTILES + blockIdx.x;       // 0..1919
    const int wid   = (lin & 7) * (NWG >> 3) + (lin >> 3);
    const int mtile = wid / NTILES;
    const int ntile = wid - mtile * NTILES;

    const int4 ti = tinfo[mtile];
    const int rows = ti.z;
    if (rows == 0) return;
    const int e      = ti.x;
    const int tstart = ti.y;
    const int n0     = ntile * BN;

    const bf16* a_base  = xb  + (size_t)tstart * KDIM;
    const bf16* b_base  = wT  + ((size_t)e * NDIM + n0) * KDIM;
    const bf16* wa_base = waT + (size_t)e * RDIM * KDIM;
    const float* wbb_e  = w_b + (size_t)e * RDIM * NDIM;

    f32x4 acc[4][4];
    f32x4 accA[4];
    #pragma unroll
    for (int i = 0; i < 4; ++i) {
        accA[i] = (f32x4){0.f, 0.f, 0.f, 0.f};
        #pragma unroll
        for (int j = 0; j < 4; ++j) acc[i][j] = (f32x4){0.f, 0.f, 0.f, 0.f};
    }

    // staging: each wave stages 32 rows of A and 32 rows of B (4 instrs each,
    // 8 rows/instr), waves 0-1 stage 8 rows of WaS each (1 instr).
    const int lr8 = lane >> 3;   // sub-row within 8-row chunk
    const int lg  = lane & 7;    // 16B-granule index within 128B row

    const bf16* agp[4];
    const bf16* bgp[4];
    #pragma unroll
    for (int i = 0; i < 4; ++i) {
        int r  = wave * 32 + i * 8 + lr8;
        int gr = r < rows ? r : rows - 1;            // clamp ragged tail
        agp[i] = a_base + (size_t)gr * KDIM + ((lg ^ (r & 7)) << 3);
        bgp[i] = b_base + (size_t)r  * KDIM + ((lg ^ (r & 7)) << 3);
    }
    const bf16* wagp = wa_base + (size_t)(wave * 8 + lr8) * KDIM + ((lg ^ lr8) << 3);

    const int swzr = (lrow & 7) << 4;   // read-side XOR (row&7 == lrow&7 for all frag rows)

    for (int kk = 0; kk < KDIM; kk += BKE) {
        __syncthreads();
        #pragma unroll
        for (int i = 0; i < 4; ++i)
            GLOAD16(agp[i], &As[wave * 32 + i * 8][0]);
        #pragma unroll
        for (int i = 0; i < 4; ++i)
            GLOAD16(bgp[i], &Bs[wave * 32 + i * 8][0]);
        if (wave < 2)
            GLOAD16(wagp, &WaS[wave * 8][0]);
        #pragma unroll
        for (int i = 0; i < 4; ++i) { agp[i] += BKE; bgp[i] += BKE; }
        wagp += BKE;
        __syncthreads();

        #pragma unroll
        for (int kh = 0; kh < 2; ++kh) {
            const int cb = (kh * 64 + quad * 16) ^ swzr;
            bf16x8 af[4];
            #pragma unroll
            for (int i = 0; i < 4; ++i)
                af[i] = *reinterpret_cast<const bf16x8*>(
                            (const char*)&As[wm * 64 + i * 16 + lrow][0] + cb);
            bf16x8 wf = *reinterpret_cast<const bf16x8*>(
                            (const char*)&WaS[lrow][0] + cb);
            #pragma unroll
            for (int j = 0; j < 4; ++j) {
                bf16x8 bfr = *reinterpret_cast<const bf16x8*>(
                                 (const char*)&Bs[wn * 64 + j * 16 + lrow][0] + cb);
                #pragma unroll
                for (int i = 0; i < 4; ++i)
                    acc[i][j] = __builtin_amdgcn_mfma_f32_16x16x32_bf16(af[i], bfr, acc[i][j], 0, 0, 0);
            }
            #pragma unroll
            for (int i = 0; i < 4; ++i)
                accA[i] = __builtin_amdgcn_mfma_f32_16x16x32_bf16(af[i], wf, accA[i], 0, 0, 0);
        }
    }

    // ================= epilogue: acc += (a * SCALE) @ w_b =================
    __syncthreads();
    // a (C-layout: col=lane&15 is r, row=quad*4+reg) -> As[m][r], swizzled; pad r 16..31 with 0
    if (wn == 0) {
        #pragma unroll
        for (int i = 0; i < 4; ++i) {
            int mrow = wm * 64 + i * 16 + quad * 4;
            #pragma unroll
            for (int r = 0; r < 4; ++r) {
                int row = mrow + r;
                char* p = (char*)&As[row][0] + ((lrow * 2) ^ ((row & 7) << 4));
                *reinterpret_cast<bf16*>(p) = (bf16)(accA[i][r] * SCALE);
            }
        }
    } else {
        #pragma unroll
        for (int i = 0; i < 4; ++i) {
            int mrow = wm * 64 + i * 16 + quad * 4;
            #pragma unroll
            for (int r = 0; r < 4; ++r) {
                int row = mrow + r;
                char* p = (char*)&As[row][0] + ((32 + lrow * 2) ^ ((row & 7) << 4));
                *reinterpret_cast<bf16*>(p) = (bf16)0.f;
            }
        }
    }
    // stage w_b: [r][n] -> Bs[n][r], swizzled, zero-padded r=16..31
    {
        int n  = tid & 127;
        int r0 = (tid >> 7) * 8;
        const float* p = wbb_e + (size_t)r0 * NDIM + n0 + n;
        bf16x8 v;
        #pragma unroll
        for (int u = 0; u < 8; ++u) v[u] = (bf16)p[(size_t)u * NDIM];
        char* q = (char*)&Bs[n][0];
        *reinterpret_cast<bf16x8*>(q + ((r0 * 2) ^ ((n & 7) << 4))) = v;
        bf16x8 z = {};
        *reinterpret_cast<bf16x8*>(q + ((32 + r0 * 2) ^ ((n & 7) << 4))) = z;
    }
    __syncthreads();
    #pragma unroll
    for (int i = 0; i < 4; ++i) {
        const int cb2 = (quad * 16) ^ swzr;
        bf16x8 af2 = *reinterpret_cast<const bf16x8*>(
                         (const char*)&As[wm * 64 + i * 16 + lrow][0] + cb2);
        #pragma unroll
        for (int j = 0; j < 4; ++j) {
            bf16x8 bf2 = *reinterpret_cast<const bf16x8*>(
                             (const char*)&Bs[wn * 64 + j * 16 + lrow][0] + cb2);
            acc[i][j] = __builtin_amdgcn_mfma_f32_16x16x32_bf16(af2, bf2, acc[i][j], 0, 0, 0);
        }
    }

    // ---- store (mask rows beyond this expert's tile) ----
    #pragma unroll
    for (int i = 0; i < 4; ++i) {
        int mbase = wm * 64 + i * 16 + quad * 4;
        #pragma unroll
        for (int j = 0; j < 4; ++j) {
            int col = n0 + wn * 64 + j * 16 + lrow;
            #pragma unroll
            for (int r = 0; r < 4; ++r) {
                int mr = mbase + r;
                if (mr < rows)
                    out[(size_t)(tstart + mr) * NDIM + col] = acc[i][j][r];
            }
        }
    }
}

// ============================================================================
// Fallback (verified previous kernel) — used if workspace is too small.
// ============================================================================
__global__ __launch_bounds__(256, 2)
void lora_moe_kernel(const float* __restrict__ x,
                     const int* __restrict__ m_sizes,
                     const float* __restrict__ w_base,
                     const float* __restrict__ w_a,
                     const float* __restrict__ w_b,
                     float* __restrict__ out)
{
    __shared__ bf16 As[BM][PK];
    __shared__ bf16 Bs[BN][PK];
    __shared__ bf16 WaS[RDIM][PK];

    const int tid  = threadIdx.x;
    const int lane = tid & 63;
    const int wave = tid >> 6;
    const int wm   = wave >> 1;
    const int wn   = wave & 1;
    const int quad = lane >> 4;
    const int lrow = lane & 15;

    int tile = blockIdx.y;
    int e = -1, tstart = 0, rows = 0;
    {
        int row0 = 0, acc2 = 0;
        for (int i = 0; i < EDIM; ++i) {
            int m = m_sizes[i];
            int nt = (m + BM - 1) >> 7;
            if (tile < acc2 + nt) {
                e = i;
                int lt = tile - acc2;
                tstart = row0 + (lt << 7);
                rows = m - (lt << 7);
                if (rows > BM) rows = BM;
                break;
            }
            acc2 += nt;
            row0 += m;
        }
    }
    if (e < 0) return;

    const int n0 = blockIdx.x * BN;

    const float* wb_e  = w_base + (size_t)e * KDIM * NDIM;
    const float* wa_e  = w_a    + (size_t)e * KDIM * RDIM;
    const float* wbb_e = w_b    + (size_t)e * RDIM * NDIM;

    f32x4 acc[4][4];
    f32x4 accA[4];
    #pragma unroll
    for (int i = 0; i < 4; ++i) {
        accA[i] = (f32x4){0.f, 0.f, 0.f, 0.f};
        #pragma unroll
        for (int j = 0; j < 4; ++j) acc[i][j] = (f32x4){0.f, 0.f, 0.f, 0.f};
    }

    const int arow  = tid >> 1;
    const int akh   = (tid & 1) * 16;
    const int agrow = tstart + (arow < rows ? arow : rows - 1);
    const float* aptr = x + (size_t)agrow * KDIM + akh;

    const int bn  = tid & 127;
    const int bg0 = (tid >> 7) * 4;

    const int war = tid & 15;
    const int wag = tid >> 4;

    for (int kk = 0; kk < KDIM; kk += 32) {
        __syncthreads();
        {
            const float* p = aptr + kk;
            float4 f0 = *reinterpret_cast<const float4*>(p);
            float4 f1 = *reinterpret_cast<const float4*>(p + 4);
            float4 f2 = *reinterpret_cast<const float4*>(p + 8);
            float4 f3 = *reinterpret_cast<const float4*>(p + 12);
            bf16x8 v0, v1;
            v0[0]=(bf16)f0.x; v0[1]=(bf16)f0.y; v0[2]=(bf16)f0.z; v0[3]=(bf16)f0.w;
            v0[4]=(bf16)f1.x; v0[5]=(bf16)f1.y; v0[6]=(bf16)f1.z; v0[7]=(bf16)f1.w;
            v1[0]=(bf16)f2.x; v1[1]=(bf16)f2.y; v1[2]=(bf16)f2.z; v1[3]=(bf16)f2.w;
            v1[4]=(bf16)f3.x; v1[5]=(bf16)f3.y; v1[6]=(bf16)f3.z; v1[7]=(bf16)f3.w;
            *reinterpret_cast<bf16x8*>(&As[arow][akh])     = v0;
            *reinterpret_cast<bf16x8*>(&As[arow][akh + 8]) = v1;
        }
        {
            #pragma unroll
            for (int gi = 0; gi < 4; ++gi) {
                int k = (bg0 + gi) * 4;
                const float* p = wb_e + (size_t)(kk + k) * NDIM + n0 + bn;
                float a0 = p[0];
                float a1 = p[NDIM];
                float a2 = p[2 * NDIM];
                float a3 = p[3 * NDIM];
                bf16x4 v; v[0]=(bf16)a0; v[1]=(bf16)a1; v[2]=(bf16)a2; v[3]=(bf16)a3;
                *reinterpret_cast<bf16x4*>(&Bs[bn][k]) = v;
            }
        }
        if (wag < 8) {
            int k = wag * 4;
            const float* p = wa_e + (size_t)(kk + k) * RDIM + war;
            bf16x4 v;
            v[0]=(bf16)p[0]; v[1]=(bf16)p[RDIM]; v[2]=(bf16)p[2*RDIM]; v[3]=(bf16)p[3*RDIM];
            *reinterpret_cast<bf16x4*>(&WaS[war][k]) = v;
        }
        __syncthreads();
        bf16x8 af[4];
        #pragma unroll
        for (int i = 0; i < 4; ++i)
            af[i] = *reinterpret_cast<const bf16x8*>(&As[wm*64 + i*16 + lrow][quad*8]);
        bf16x8 wf = *reinterpret_cast<const bf16x8*>(&WaS[lrow][quad*8]);
        #pragma unroll
        for (int j = 0; j < 4; ++j) {
            bf16x8 bfr = *reinterpret_cast<const bf16x8*>(&Bs[wn*64 + j*16 + lrow][quad*8]);
            #pragma unroll
            for (int i = 0; i < 4; ++i)
                acc[i][j] = __builtin_amdgcn_mfma_f32_16x16x32_bf16(af[i], bfr, acc[i][j], 0, 0, 0);
        }
        #pragma unroll
        for (int i = 0; i < 4; ++i)
            accA[i] = __builtin_amdgcn_mfma_f32_16x16x32_bf16(af[i], wf, accA[i], 0, 0, 0);
    }

    __syncthreads();
    if (wn == 0) {
        #pragma unroll
        for (int i = 0; i < 4; ++i) {
            int mrow = wm*64 + i*16 + quad*4;
            #pragma unroll
            for (int r = 0; r < 4; ++r)
                As[mrow + r][lrow] = (bf16)(accA[i][r] * SCALE);
        }
    } else {
        #pragma unroll
        for (int i = 0; i < 4; ++i) {
            int mrow = wm*64 + i*16 + quad*4;
            #pragma unroll
            for (int r = 0; r < 4; ++r)
                As[mrow + r][16 + lrow] = (bf16)0.f;
        }
    }
    {
        int n  = tid & 127;
        int r0 = (tid >> 7) * 8;
        const float* p = wbb_e + (size_t)r0 * NDIM + n0 + n;
        bf16x8 v;
        #pragma unroll
        for (int u = 0; u < 8; ++u) v[u] = (bf16)p[(size_t)u * NDIM];
        *reinterpret_cast<bf16x8*>(&Bs[n][r0]) = v;
        bf16x8 z = {};
        *reinterpret_cast<bf16x8*>(&Bs[n][16 + r0]) = z;
    }
    __syncthreads();
    #pragma unroll
    for (int i = 0; i < 4; ++i) {
        bf16x8 af2 = *reinterpret_cast<const bf16x8*>(&As[wm*64 + i*16 + lrow][quad*8]);
        #pragma unroll
        for (int j = 0; j < 4; ++j) {
            bf16x8 bf2 = *reinterpret_cast<const bf16x8*>(&Bs[wn*64 + j*16 + lrow][quad*8]);
            acc[i][j] = __builtin_amdgcn_mfma_f32_16x16x32_bf16(af2, bf2, acc[i][j], 0, 0, 0);
        }
    }

    #pragma unroll
    for (int i = 0; i < 4; ++i) {
        int mbase = wm*64 + i*16 + quad*4;
        #pragma unroll
        for (int j = 0; j < 4; ++j) {
            int col = n0 + wn*64 + j*16 + lrow;
            #pragma unroll
            for (int r = 0; r < 4; ++r) {
                int mr = mbase + r;
                if (mr < rows)
                    out[(size_t)(tstart + mr) * NDIM + col] = acc[i][j][r];
            }
        }
    }
}

extern "C" void kernel_launch(void* const* d_in, const int* in_sizes, int n_in,
                              void* d_out, int out_size, void* d_ws, size_t ws_size,
                              hipStream_t stream) {
    const float* x       = (const float*)d_in[0];
    const int*   m_sizes = (const int*)  d_in[1];
    const float* w_base  = (const float*)d_in[2];
    const float* w_a     = (const float*)d_in[3];
    const float* w_b     = (const float*)d_in[4];
    float* out = (float*)d_out;

    const size_t off_xb  = 0;
    const size_t off_wT  = off_xb  + (size_t)TDIM * KDIM * sizeof(bf16);          // 128 MiB
    const size_t off_waT = off_wT  + (size_t)EDIM * NDIM * KDIM * sizeof(bf16);   // +192 MiB
    const size_t off_ti  = off_waT + (size_t)EDIM * RDIM * KDIM * sizeof(bf16);   // +4 MiB
    const size_t need    = off_ti  + (size_t)MAXMT * sizeof(int4);

    if (ws_size >= need) {
        bf16* xb   = (bf16*)((char*)d_ws + off_xb);
        bf16* wT   = (bf16*)((char*)d_ws + off_wT);
        bf16* waT  = (bf16*)((char*)d_ws + off_waT);
        int4* tinf = (int4*)((char*)d_ws + off_ti);

        conv_x_k<<<(TDIM * KDIM) / (256 * 8), 256, 0, stream>>>(x, xb);
        conv_w_k<<<dim3(NDIM / 64, KDIM / 64, EDIM), 256, 0, stream>>>(w_base, wT);
        prep_small_k<<<dim3(17, EDIM), 256, 0, stream>>>(w_a, m_sizes, waT, tinf);
        lora_moe_bf16<<<dim3(NTILES, MAXMT), 256, 0, stream>>>(xb, wT, waT, w_b, tinf, out);
    } else {
        lora_moe_kernel<<<dim3(NTILES, MAXMT), 256, 0, stream>>>(x, m_sizes, w_base, w_a, w_b, out);
    }
}